// Round 5
// baseline (241.393 us; speedup 1.0000x reference)
//
#include <hip/hip_runtime.h>
#include <hip/hip_bf16.h>

typedef unsigned short u16;
typedef __bf16 bf16x8 __attribute__((ext_vector_type(8)));
typedef short s16x4 __attribute__((ext_vector_type(4)));
typedef float f32x4 __attribute__((ext_vector_type(4)));

__device__ __forceinline__ f32x4 mfma16(bf16x8 a, bf16x8 b, f32x4 c) {
    return __builtin_amdgcn_mfma_f32_16x16x32_bf16(a, b, c, 0, 0, 0);
}
__device__ __forceinline__ f32x4 mfma16k16(s16x4 a, s16x4 b, f32x4 c) {
    return __builtin_amdgcn_mfma_f32_16x16x16bf16_1k(a, b, c, 0, 0, 0);
}

// fp32 -> bf16 bits, round-to-nearest-even
__device__ __forceinline__ u16 f2b(float x) {
    union { float f; unsigned u; } a; a.f = x;
    unsigned r = a.u + 0x7fffu + ((a.u >> 16) & 1u);
    return (u16)(r >> 16);
}
// packed pair (RTNE, identical result to f2b per element)
__device__ __forceinline__ unsigned f2b2(float a, float b) {
    union { __hip_bfloat162 h; unsigned u; } cv;
    cv.h = __float22bfloat162_rn(make_float2(a, b));
    return cv.u;
}

// ---------------- fused cast fp32 -> bf16 for all three inputs ----------------
#define NX  (8192 * 512)
#define NWQ (1536 * 512)
#define NWO (512 * 512)
__global__ __launch_bounds__(256) void k_cast_all(const float* __restrict__ x,
                                                  const float* __restrict__ wq,
                                                  const float* __restrict__ wo,
                                                  u16* __restrict__ xb,
                                                  u16* __restrict__ wqb,
                                                  u16* __restrict__ wob) {
    int i = (blockIdx.x * 256 + threadIdx.x) * 4;
    const float* s; u16* d; int off;
    if (i < NX)            { s = x;  d = xb;  off = i; }
    else if (i < NX + NWQ) { s = wq; d = wqb; off = i - NX; }
    else                   { s = wo; d = wob; off = i - NX - NWQ; }
    float4 f = *(const float4*)&s[off];
    uint2 o = make_uint2(f2b2(f.x, f.y), f2b2(f.z, f.w));
    *(uint2*)&d[off] = o;
}

// ---------------- QKV GEMM: [8192,512]bf16 x [1536,512]bf16^T ----------------
// q,k -> [B*H][S][64] bf16 (q pre-scaled 0.125/ln2)
// v   -> VF[bh][kt][nt][mb][quad][l15][4]  (PV A-fragment order, perfectly coalesced)
__global__ __launch_bounds__(256) void k_gemm_qkv(const u16* __restrict__ xb,
                                                  const u16* __restrict__ wb,
                                                  const float* __restrict__ bias,
                                                  u16* __restrict__ qkvout) {
    __shared__ u16 As[128][40];
    __shared__ u16 Ws[128][40];
    const int tid = threadIdx.x;
    const int w = tid >> 6, lane = tid & 63, l15 = lane & 15, quad = lane >> 4;
    const int mb = blockIdx.x * 128, nb = blockIdx.y * 128;

    f32x4 acc[2][8];
#pragma unroll
    for (int i = 0; i < 2; i++)
#pragma unroll
        for (int j = 0; j < 8; j++) acc[i][j] = (f32x4){0.f, 0.f, 0.f, 0.f};

    for (int k0 = 0; k0 < 512; k0 += 32) {
        {
            int row = tid >> 1, cc = (tid & 1) * 16;
            const u16* g = &xb[(size_t)(mb + row) * 512 + k0 + cc];
            *(uint4*)&As[row][cc]     = *(const uint4*)g;
            *(uint4*)&As[row][cc + 8] = *(const uint4*)(g + 8);
            const u16* gw = &wb[(size_t)(nb + row) * 512 + k0 + cc];
            *(uint4*)&Ws[row][cc]     = *(const uint4*)gw;
            *(uint4*)&Ws[row][cc + 8] = *(const uint4*)(gw + 8);
        }
        __syncthreads();
        bf16x8 a0 = *(const bf16x8*)&As[w * 32 + l15][quad * 8];
        bf16x8 a1 = *(const bf16x8*)&As[w * 32 + 16 + l15][quad * 8];
#pragma unroll
        for (int nt = 0; nt < 8; nt++) {
            bf16x8 bfr = *(const bf16x8*)&Ws[nt * 16 + l15][quad * 8];
            acc[0][nt] = mfma16(a0, bfr, acc[0][nt]);
            acc[1][nt] = mfma16(a1, bfr, acc[1][nt]);
        }
        __syncthreads();
    }
    const int seg = nb >> 9;          // 0=q 1=k 2=v (128-tile stays in one seg)
    u16* obase = qkvout + (size_t)seg * (16ull * 4096 * 64);
    if (seg < 2) {
        const float sc = (seg == 0) ? 0.125f * 1.44269504088896340736f : 1.0f;
#pragma unroll
        for (int mt = 0; mt < 2; mt++)
#pragma unroll
            for (int nt = 0; nt < 8; nt++) {
                int dcol = nb + nt * 16 + l15;
                int hh = (dcol >> 6) & 7, dloc = dcol & 63;
                float bs = bias[dcol];
#pragma unroll
                for (int r = 0; r < 4; r++) {
                    int m = mb + w * 32 + mt * 16 + quad * 4 + r;
                    float vv = (acc[mt][nt][r] + bs) * sc;
                    int b = m >> 12, s = m & 4095;
                    obase[((size_t)((b * 8 + hh) * 4096 + s)) * 64 + dloc] = f2b(vv);
                }
            }
    } else {
        // V in PV-A-frag order: F4 = ((((bh*64+kt)*4+ntv)*4+mbv)*4+quad)*16+l15v, +r elementwise
#pragma unroll
        for (int mt = 0; mt < 2; mt++)
#pragma unroll
            for (int nt = 0; nt < 8; nt++) {
                int c = nb + nt * 16 + l15;
                int hh = (c >> 6) & 7, d = c & 63;
                int mbv = d >> 4, l15v = d & 15;
                float bs = bias[c];
                int m0 = mb + w * 32 + mt * 16 + quad * 4;
                int b = m0 >> 12, si = m0 & 4095;
                int kt = si >> 6, ka = si & 63;
                int ntv = ka >> 4;                 // quadv == quad, r == ka&3 offset
                uint2 o = make_uint2(f2b2(acc[mt][nt][0] + bs, acc[mt][nt][1] + bs),
                                     f2b2(acc[mt][nt][2] + bs, acc[mt][nt][3] + bs));
                size_t F4 = ((((((size_t)(b * 8 + hh) * 64 + kt) * 4 + ntv) * 4 + mbv) * 4 + quad) * 16 + l15v);
                *(uint2*)&obase[F4 * 4] = o;
            }
    }
}

// ---------------- flash attention v5 (inverted-window mask) -----------------
// block = 128 thr = 2 waves x 32 q-rows. Only K goes through LDS (8KB dbuf,
// XOR chunk-swizzled, single barrier/iter). V frags load straight from global
// in A-frag order (coalesced dwordx2, imm offsets). P stays in registers.
__global__ __launch_bounds__(128, 2) void k_attn(const u16* __restrict__ qkv,
                                                 const u16* __restrict__ vfg,
                                                 u16* __restrict__ ctx,
                                                 const int* __restrict__ win) {
    __shared__ u16 Ks[2][64][64];
    const int tid = threadIdx.x;
    const int w = tid >> 6, lane = tid & 63, l15 = lane & 15, quad = lane >> 4;
    const int bh = blockIdx.y;
    const int qb0 = blockIdx.x * 64;
    const int W = win[0];
    const u16* qg = qkv;
    const u16* kg = qkv + 16ull * 4096 * 64;
    const size_t bhb = (size_t)bh * 4096 * 64;

    // Q fragments: B-operand of S^T = K*Q^T
    bf16x8 qf[2][2];
#pragma unroll
    for (int g = 0; g < 2; g++) {
        const u16* qrow = &qg[bhb + (size_t)(qb0 + w * 32 + g * 16 + l15) * 64];
        qf[g][0] = *(const bf16x8*)&qrow[quad * 8];
        qf[g][1] = *(const bf16x8*)&qrow[32 + quad * 8];
    }

    f32x4 O[2][4];
#pragma unroll
    for (int g = 0; g < 2; g++)
#pragma unroll
        for (int mb = 0; mb < 4; mb++) O[g][mb] = (f32x4){0.f, 0.f, 0.f, 0.f};
    float lsum[2] = {0.f, 0.f};

    const int srow = tid >> 1, half = tid & 1, sw = srow & 7;
    const u16* kgr = &kg[bhb + (size_t)srow * 64 + half * 32];
    const u16* vb0 = vfg + (size_t)bh * 64 * 4096 + lane * 4;

    int it = 0;
    for (int kb = 0; kb < 4096; kb += 64) {
        if (max(qb0 + 63 - kb, kb + 63 - qb0) <= W) continue;  // fully masked tile
        bool partial = (kb + 63 >= qb0 - W) && (kb <= qb0 + 63 + W);
        int p = it & 1; it++;
        // V fragment loads (global, A-frag order; issued early = prefetch)
        const u16* vt0 = vb0 + (size_t)(kb >> 6) * 4096;
        const u16* vt1 = vt0 + 2048;
        s16x4 vfr[16];
#pragma unroll
        for (int f = 0; f < 8; f++) vfr[f]     = *(const s16x4*)&vt0[f * 256];
#pragma unroll
        for (int f = 0; f < 8; f++) vfr[f + 8] = *(const s16x4*)&vt1[f * 256];
        // K tile: global -> regs -> swizzled LDS (chunk c' = c ^ (row&7))
        {
            const u16* kp = kgr + (size_t)kb * 64;
            uint4 kr0 = *(const uint4*)kp;
            uint4 kr1 = *(const uint4*)(kp + 8);
            uint4 kr2 = *(const uint4*)(kp + 16);
            uint4 kr3 = *(const uint4*)(kp + 24);
            int cb = half * 4;
            *(uint4*)&Ks[p][srow][((cb + 0) ^ sw) * 8] = kr0;
            *(uint4*)&Ks[p][srow][((cb + 1) ^ sw) * 8] = kr1;
            *(uint4*)&Ks[p][srow][((cb + 2) ^ sw) * 8] = kr2;
            *(uint4*)&Ks[p][srow][((cb + 3) ^ sw) * 8] = kr3;
        }
        __syncthreads();
        // K fragments (A of S^T), swizzle-corrected reads
        bf16x8 kf[4][2];
        const int rs = l15 & 7;
#pragma unroll
        for (int nt = 0; nt < 4; nt++) {
            kf[nt][0] = *(const bf16x8*)&Ks[p][nt * 16 + l15][(quad ^ rs) * 8];
            kf[nt][1] = *(const bf16x8*)&Ks[p][nt * 16 + l15][((quad + 4) ^ rs) * 8];
        }
#pragma unroll
        for (int g = 0; g < 2; g++) {
            f32x4 C[4];
#pragma unroll
            for (int nt = 0; nt < 4; nt++) {
                f32x4 z = (f32x4){0.f, 0.f, 0.f, 0.f};
                C[nt] = mfma16(kf[nt][0], qf[g][0], z);
                C[nt] = mfma16(kf[nt][1], qf[g][1], C[nt]);
            }
            // p = 2^s; masked -> 0; pack into PV B-frags (registers only)
            s16x4 pb[4];
            if (!partial) {
#pragma unroll
                for (int nt = 0; nt < 4; nt++) {
                    float p0 = __builtin_amdgcn_exp2f(C[nt][0]);
                    float p1 = __builtin_amdgcn_exp2f(C[nt][1]);
                    float p2 = __builtin_amdgcn_exp2f(C[nt][2]);
                    float p3 = __builtin_amdgcn_exp2f(C[nt][3]);
                    lsum[g] += (p0 + p1) + (p2 + p3);
                    union { uint2 u; s16x4 v; } pk;
                    pk.u = make_uint2(f2b2(p0, p1), f2b2(p2, p3));
                    pb[nt] = pk.v;
                }
            } else {
                int qr = qb0 + w * 32 + g * 16 + l15;
#pragma unroll
                for (int nt = 0; nt < 4; nt++) {
                    float pv[4];
#pragma unroll
                    for (int r = 0; r < 4; r++) {
                        int key = kb + nt * 16 + quad * 4 + r;
                        int dd = qr - key; dd = dd < 0 ? -dd : dd;
                        pv[r] = (dd <= W) ? 0.f : __builtin_amdgcn_exp2f(C[nt][r]);
                        lsum[g] += pv[r];
                    }
                    union { uint2 u; s16x4 v; } pk;
                    pk.u = make_uint2(f2b2(pv[0], pv[1]), f2b2(pv[2], pv[3]));
                    pb[nt] = pk.v;
                }
            }
            // O^T += V^T * P^T  (A-frags straight from global)
#pragma unroll
            for (int nt = 0; nt < 4; nt++)
#pragma unroll
                for (int mb = 0; mb < 4; mb++)
                    O[g][mb] = mfma16k16(vfr[nt * 4 + mb], pb[nt], O[g][mb]);
        }
    }
    // deferred row-sums: lsum lives at qrow=l15, matching O^T col=l15
#pragma unroll
    for (int g = 0; g < 2; g++) {
        lsum[g] += __shfl_xor(lsum[g], 16);
        lsum[g] += __shfl_xor(lsum[g], 32);
    }
    int b = bh >> 3, h = bh & 7;
#pragma unroll
    for (int g = 0; g < 2; g++) {
        float inv = 1.0f / lsum[g];
        int qr = qb0 + w * 32 + g * 16 + l15;
        size_t rowoff = ((size_t)(b * 4096 + qr)) * 512 + h * 64;
#pragma unroll
        for (int mb = 0; mb < 4; mb++) {
            uint2 o = make_uint2(f2b2(O[g][mb][0] * inv, O[g][mb][1] * inv),
                                 f2b2(O[g][mb][2] * inv, O[g][mb][3] * inv));
            *(uint2*)&ctx[rowoff + mb * 16 + quad * 4] = o;
        }
    }
}

// ---------------- out GEMM: ctx[8192,512]bf16 x wout[512,512]bf16^T + bias -> fp32 ----
// 128x64 tiles, grid (64,8)=512 blocks -> 2 blocks/CU
__global__ __launch_bounds__(256) void k_gemm_out(const u16* __restrict__ ab,
                                                  const u16* __restrict__ wb,
                                                  const float* __restrict__ bias,
                                                  float* __restrict__ out) {
    __shared__ u16 As[128][40];
    __shared__ u16 Ws[64][40];
    const int tid = threadIdx.x;
    const int w = tid >> 6, lane = tid & 63, l15 = lane & 15, quad = lane >> 4;
    const int mb = blockIdx.x * 128, nb = blockIdx.y * 64;

    f32x4 acc[2][4];
#pragma unroll
    for (int i = 0; i < 2; i++)
#pragma unroll
        for (int j = 0; j < 4; j++) acc[i][j] = (f32x4){0.f, 0.f, 0.f, 0.f};

    for (int k0 = 0; k0 < 512; k0 += 32) {
        {
            int row = tid >> 1, cc = (tid & 1) * 16;
            const u16* g = &ab[(size_t)(mb + row) * 512 + k0 + cc];
            *(uint4*)&As[row][cc]     = *(const uint4*)g;
            *(uint4*)&As[row][cc + 8] = *(const uint4*)(g + 8);
            int wrow = tid >> 2, wcc = (tid & 3) * 8;
            *(uint4*)&Ws[wrow][wcc] = *(const uint4*)&wb[(size_t)(nb + wrow) * 512 + k0 + wcc];
        }
        __syncthreads();
        bf16x8 a0 = *(const bf16x8*)&As[w * 32 + l15][quad * 8];
        bf16x8 a1 = *(const bf16x8*)&As[w * 32 + 16 + l15][quad * 8];
#pragma unroll
        for (int nt = 0; nt < 4; nt++) {
            bf16x8 bfr = *(const bf16x8*)&Ws[nt * 16 + l15][quad * 8];
            acc[0][nt] = mfma16(a0, bfr, acc[0][nt]);
            acc[1][nt] = mfma16(a1, bfr, acc[1][nt]);
        }
        __syncthreads();
    }
#pragma unroll
    for (int mt = 0; mt < 2; mt++)
#pragma unroll
        for (int nt = 0; nt < 4; nt++) {
            int n = nb + nt * 16 + l15;
            float bs = bias[n];
#pragma unroll
            for (int r = 0; r < 4; r++) {
                int m = mb + w * 32 + mt * 16 + quad * 4 + r;
                out[(size_t)m * 512 + n] = acc[mt][nt][r] + bs;
            }
        }
}

extern "C" void kernel_launch(void* const* d_in, const int* in_sizes, int n_in,
                              void* d_out, int out_size, void* d_ws, size_t ws_size,
                              hipStream_t stream) {
    const float* x    = (const float*)d_in[0];
    const float* wqkv = (const float*)d_in[1];
    const float* bqkv = (const float*)d_in[2];
    const float* wout = (const float*)d_in[3];
    const float* bout = (const float*)d_in[4];
    const int*   win  = (const int*)d_in[5];
    float* out = (float*)d_out;

    u16* xb    = (u16*)d_ws;
    u16* wqkvb = xb    + 8192ull * 512;
    u16* woutb = wqkvb + 1536ull * 512;
    u16* qkvb  = woutb + 512ull * 512;
    u16* ctxb  = qkvb  + 3ull * 16 * 4096 * 64;

    k_cast_all<<<5120, 256, 0, stream>>>(x, wqkv, wout, xb, wqkvb, woutb);
    k_gemm_qkv<<<dim3(64, 12), 256, 0, stream>>>(xb, wqkvb, bqkv, qkvb);
    k_attn<<<dim3(64, 16), 128, 0, stream>>>(qkvb, qkvb + 32ull * 4096 * 64, ctxb, win);
    k_gemm_out<<<dim3(64, 8), 256, 0, stream>>>(ctxb, woutb, bout, out);
}